// Round 2
// baseline (1537.675 us; speedup 1.0000x reference)
//
#include <hip/hip_runtime.h>

#define BATCH 2048
#define IN    256
#define OUTD  256
#define NC    11   // NUM + K = 8 + 3

__global__ __launch_bounds__(256, 4) void kan_main(
    const float* __restrict__ x, const float* __restrict__ coef,
    const float* __restrict__ sb, const float* __restrict__ ss,
    const float* __restrict__ mk, float* __restrict__ out)
{
    __shared__ float4 v_s[IN];          // cubic B-spline basis values per i
    __shared__ float  base_s[IN];       // silu(xn)
    __shared__ int    comb_s[IN];       // i*OUTD*NC + idx
    __shared__ float4 xn4_s[IN / 4];    // xn values (for preacts), float4-aligned

    const int b = blockIdx.x;
    const int t = threadIdx.x;

    // ---- Phase A: per-input-dim scalars ----
    {
        float xv  = x[(size_t)b * IN + t];
        // shift=0, scal=1: xn = tanh(2x)
        float xn  = tanhf(2.0f * xv);
        float sig = 1.0f / (1.0f + expf(-xn));
        float base = xn * sig;
        // h = 0.25 ; pos = (xn+1)*4
        float pos  = (xn + 1.0f) * 4.0f;
        float fidx = fminf(fmaxf(floorf(pos), 0.0f), 7.0f);
        float u    = pos - fidx;
        int   idx  = (int)fidx;
        float u2 = u * u, u3 = u2 * u;
        const float c6 = 1.0f / 6.0f;
        float4 v;
        v.x = (1.0f - 3.0f * u + 3.0f * u2 - u3) * c6;   // (1-u)^3/6
        v.y = (4.0f - 6.0f * u2 + 3.0f * u3) * c6;
        v.z = (1.0f + 3.0f * u + 3.0f * u2 - 3.0f * u3) * c6;
        v.w = u3 * c6;
        v_s[t]    = v;
        base_s[t] = base;
        comb_s[t] = t * (OUTD * NC) + idx;
        ((float*)xn4_s)[t] = xn;
    }
    __syncthreads();

    // output layout (f32 elements): y | preacts | postacts | postspline
    float* y    = out;
    float* pre  = out + (size_t)BATCH * OUTD;
    float* pact = pre  + (size_t)BATCH * OUTD * IN;
    float* pspl = pact + (size_t)BATCH * OUTD * IN;

    const int o = t;
    const size_t rowoff = (size_t)b * OUTD * IN + (size_t)o * IN;

    // ---- preacts[b][o][i] = xn[b][i] ----
    {
        float4* dst = (float4*)(pre + rowoff);
        #pragma unroll
        for (int c = 0; c < IN / 4; ++c) dst[c] = xn4_s[c];
    }

    // ---- main loop over input dims ----
    float yacc = 0.0f;
    const int oNC = o * NC;
    for (int i0 = 0; i0 < IN; i0 += 4) {
        float psa[4], paa[4];
        #pragma unroll
        for (int ii = 0; ii < 4; ++ii) {
            const int i = i0 + ii;
            float4 v = v_s[i];
            const float* cp = coef + comb_s[i] + oNC;
            float spl = cp[0] * v.x + cp[1] * v.y + cp[2] * v.z + cp[3] * v.w;
            const int io = i * OUTD + o;
            float yf = mk[io] * (sb[io] * base_s[i] + ss[io] * spl);
            yacc += yf;
            psa[ii] = spl;
            paa[ii] = yf;
        }
        *(float4*)(pspl + rowoff + i0) = *(float4*)psa;
        *(float4*)(pact + rowoff + i0) = *(float4*)paa;
    }

    y[(size_t)b * OUTD + o] = yacc;
}

extern "C" void kernel_launch(void* const* d_in, const int* in_sizes, int n_in,
                              void* d_out, int out_size, void* d_ws, size_t ws_size,
                              hipStream_t stream) {
    const float* x    = (const float*)d_in[0];
    const float* coef = (const float*)d_in[1];
    const float* sb   = (const float*)d_in[2];
    const float* ss   = (const float*)d_in[3];
    const float* mk   = (const float*)d_in[4];
    float* out = (float*)d_out;

    kan_main<<<BATCH, 256, 0, stream>>>(x, coef, sb, ss, mk, out);
}

// Round 3
// 636.291 us; speedup vs baseline: 2.4166x; 2.4166x over previous
//
#include <hip/hip_runtime.h>

#define BATCH 2048
#define IN    256
#define OUTD  256
#define NC    11   // NUM + K = 8 + 3
#define IC    16   // i-chunk staged in LDS
#define ICP   17   // padded tile row stride (odd -> ~2-way bank aliasing, free)

__global__ __launch_bounds__(256, 3) void kan_main(
    const float* __restrict__ x, const float* __restrict__ coef,
    const float* __restrict__ sb, const float* __restrict__ ss,
    const float* __restrict__ mk, float* __restrict__ out)
{
    __shared__ float4 v_s[IN];          // cubic B-spline basis values per i
    __shared__ float  base_s[IN];       // silu(xn)
    __shared__ int    comb_s[IN];       // i*OUTD*NC + idx
    __shared__ float  xn_s[IN];         // xn (for preacts)
    __shared__ float  ps_t[OUTD * ICP]; // postspline tile [o][ii]
    __shared__ float  pa_t[OUTD * ICP]; // postacts tile   [o][ii]

    const int b = blockIdx.x;
    const int t = threadIdx.x;

    // ---- Phase A: per-input-dim scalars (thread = i) ----
    {
        float xv  = x[(size_t)b * IN + t];
        float xn  = tanhf(2.0f * xv);          // shift=0, scal=1
        float sig = 1.0f / (1.0f + expf(-xn));
        float base = xn * sig;
        float pos  = (xn + 1.0f) * 4.0f;       // h = 0.25
        float fidx = fminf(fmaxf(floorf(pos), 0.0f), 7.0f);
        float u    = pos - fidx;
        int   idx  = (int)fidx;
        float u2 = u * u, u3 = u2 * u;
        const float c6 = 1.0f / 6.0f;
        float4 v;
        v.x = (1.0f - 3.0f * u + 3.0f * u2 - u3) * c6;
        v.y = (4.0f - 6.0f * u2 + 3.0f * u3) * c6;
        v.z = (1.0f + 3.0f * u + 3.0f * u2 - 3.0f * u3) * c6;
        v.w = u3 * c6;
        v_s[t]    = v;
        base_s[t] = base;
        comb_s[t] = t * (OUTD * NC) + idx;
        xn_s[t]   = xn;
    }
    __syncthreads();

    // output layout (f32): y | preacts | postacts | postspline
    float* y    = out;
    float* pre  = out + (size_t)BATCH * OUTD;
    float* pact = pre  + (size_t)BATCH * OUTD * IN;
    float* pspl = pact + (size_t)BATCH * OUTD * IN;

    // ---- preacts[b][o][i] = xn[i]: coalesced column-strided stores ----
    // float4 index f = c*256 + t  ->  o = f>>6, ii4 = f&63 = t&63 (const per thread)
    {
        float4 myxn = ((const float4*)xn_s)[t & 63];
        float4* dst = (float4*)(pre + (size_t)b * OUTD * IN);
        #pragma unroll 8
        for (int c = 0; c < 64; ++c) dst[c * 256 + t] = myxn;  // 1KB contiguous / wave inst
    }

    // ---- main loop: compute (thread = o) into LDS tile, write back coalesced ----
    float yacc = 0.0f;
    const int o = t;
    const int oNC = o * NC;
    const size_t bbase = (size_t)b * OUTD * IN;

    for (int ic = 0; ic < IN / IC; ++ic) {
        #pragma unroll
        for (int ii = 0; ii < IC; ++ii) {
            const int i = ic * IC + ii;
            float4 v = v_s[i];
            const float* cp = coef + comb_s[i] + oNC;
            float spl = cp[0] * v.x + cp[1] * v.y + cp[2] * v.z + cp[3] * v.w;
            const int io = i * OUTD + o;
            float yf = mk[io] * (sb[io] * base_s[i] + ss[io] * spl);
            yacc += yf;
            ps_t[o * ICP + ii] = spl;
            pa_t[o * ICP + ii] = yf;
        }
        __syncthreads();
        // write 256x16 tile: f = c*256+t -> oo = f>>2, 16B chunk i4 = (f&3)*4
        // lanes 0..63 cover 16 full 64B lines per store instruction
        #pragma unroll
        for (int c = 0; c < 4; ++c) {
            const int f  = c * 256 + t;
            const int oo = f >> 2;
            const int i4 = (f & 3) * 4;
            const int la = oo * ICP + i4;
            float4 vps, vpa;
            vps.x = ps_t[la]; vps.y = ps_t[la+1]; vps.z = ps_t[la+2]; vps.w = ps_t[la+3];
            vpa.x = pa_t[la]; vpa.y = pa_t[la+1]; vpa.z = pa_t[la+2]; vpa.w = pa_t[la+3];
            const size_t g = bbase + (size_t)oo * IN + ic * IC + i4;
            *(float4*)(pspl + g) = vps;
            *(float4*)(pact + g) = vpa;
        }
        __syncthreads();
    }

    y[(size_t)b * OUTD + o] = yacc;
}

extern "C" void kernel_launch(void* const* d_in, const int* in_sizes, int n_in,
                              void* d_out, int out_size, void* d_ws, size_t ws_size,
                              hipStream_t stream) {
    const float* x    = (const float*)d_in[0];
    const float* coef = (const float*)d_in[1];
    const float* sb   = (const float*)d_in[2];
    const float* ss   = (const float*)d_in[3];
    const float* mk   = (const float*)d_in[4];
    float* out = (float*)d_out;

    kan_main<<<BATCH, 256, 0, stream>>>(x, coef, sb, ss, mk, out);
}

// Round 5
// 423.476 us; speedup vs baseline: 3.6311x; 1.5025x over previous
//
#include <hip/hip_runtime.h>

#define BATCH 2048
#define IN    256
#define OUTD  256
#define NC    11   // NUM + K = 8 + 3
#define IC    16   // i-chunk staged in LDS
#define ICP   17   // padded tile row stride

typedef __attribute__((ext_vector_type(4))) float f32x4;

// ---------- pre-pass: coefT[i][n][o] = coef[i][o][n] ----------
__global__ __launch_bounds__(256) void transpose_coef(
    const float* __restrict__ coef, float* __restrict__ coefT)
{
    __shared__ float tile[NC][OUTD];
    const int i = blockIdx.x;
    const int o = threadIdx.x;
    const float* src = coef + (size_t)i * OUTD * NC + o * NC;
    #pragma unroll
    for (int n = 0; n < NC; ++n) tile[n][o] = src[n];
    __syncthreads();
    float* dst = coefT + (size_t)i * NC * OUTD;
    #pragma unroll
    for (int n = 0; n < NC; ++n) dst[n * OUTD + o] = tile[n][o];
}

// ---------- main kernel (coefT path: coalesced coef reads) ----------
__global__ __launch_bounds__(256, 3) void kan_main(
    const float* __restrict__ x, const float* __restrict__ coefT,
    const float* __restrict__ sb, const float* __restrict__ ss,
    const float* __restrict__ mk, float* __restrict__ out)
{
    __shared__ f32x4 v_s[IN];
    __shared__ float base_s[IN];
    __shared__ int   comb_s[IN];       // i*NC*OUTD + idx*OUTD
    __shared__ float xn_s[IN];
    __shared__ float ps_t[OUTD * ICP];
    __shared__ float pa_t[OUTD * ICP];

    const int b = blockIdx.x;
    const int t = threadIdx.x;

    {
        float xv  = x[(size_t)b * IN + t];
        float xn  = tanhf(2.0f * xv);          // shift=0, scal=1
        float sig = 1.0f / (1.0f + expf(-xn));
        float base = xn * sig;
        float pos  = (xn + 1.0f) * 4.0f;       // h = 0.25
        float fidx = fminf(fmaxf(floorf(pos), 0.0f), 7.0f);
        float u    = pos - fidx;
        int   idx  = (int)fidx;
        float u2 = u * u, u3 = u2 * u;
        const float c6 = 1.0f / 6.0f;
        f32x4 v;
        v.x = (1.0f - 3.0f * u + 3.0f * u2 - u3) * c6;
        v.y = (4.0f - 6.0f * u2 + 3.0f * u3) * c6;
        v.z = (1.0f + 3.0f * u + 3.0f * u2 - 3.0f * u3) * c6;
        v.w = u3 * c6;
        v_s[t]    = v;
        base_s[t] = base;
        comb_s[t] = t * (NC * OUTD) + idx * OUTD;
        xn_s[t]   = xn;
    }
    __syncthreads();

    float* y    = out;
    float* pre  = out + (size_t)BATCH * OUTD;
    float* pact = pre  + (size_t)BATCH * OUTD * IN;
    float* pspl = pact + (size_t)BATCH * OUTD * IN;

    // preacts[b][o][i] = xn[i]: column-strided f32x4 stores, 1KB/wave-inst
    {
        f32x4 myxn = ((const f32x4*)xn_s)[t & 63];
        f32x4* dst = (f32x4*)(pre + (size_t)b * OUTD * IN);
        #pragma unroll 8
        for (int c = 0; c < 64; ++c)
            __builtin_nontemporal_store(myxn, dst + c * 256 + t);
    }

    float yacc = 0.0f;
    const int o = t;
    const size_t bbase = (size_t)b * OUTD * IN;

    for (int ic = 0; ic < IN / IC; ++ic) {
        #pragma unroll
        for (int ii = 0; ii < IC; ++ii) {
            const int i = ic * IC + ii;
            f32x4 v = v_s[i];
            const float* cp = coefT + comb_s[i] + o;   // lane-consecutive
            float spl = cp[0]        * v.x + cp[OUTD]     * v.y
                      + cp[OUTD * 2] * v.z + cp[OUTD * 3] * v.w;
            const int io = i * OUTD + o;
            float yf = mk[io] * (sb[io] * base_s[i] + ss[io] * spl);
            yacc += yf;
            ps_t[o * ICP + ii] = spl;
            pa_t[o * ICP + ii] = yf;
        }
        __syncthreads();
        #pragma unroll
        for (int c = 0; c < 4; ++c) {
            const int f  = c * 256 + t;
            const int oo = f >> 2;
            const int i4 = (f & 3) * 4;
            const int la = oo * ICP + i4;
            f32x4 vps, vpa;
            vps.x = ps_t[la]; vps.y = ps_t[la+1]; vps.z = ps_t[la+2]; vps.w = ps_t[la+3];
            vpa.x = pa_t[la]; vpa.y = pa_t[la+1]; vpa.z = pa_t[la+2]; vpa.w = pa_t[la+3];
            const size_t g = bbase + (size_t)oo * IN + ic * IC + i4;
            __builtin_nontemporal_store(vps, (f32x4*)(pspl + g));
            __builtin_nontemporal_store(vpa, (f32x4*)(pact + g));
        }
        __syncthreads();
    }

    y[(size_t)b * OUTD + o] = yacc;
}

// ---------- fallback (direct gather, no scratch needed) ----------
__global__ __launch_bounds__(256, 3) void kan_main_direct(
    const float* __restrict__ x, const float* __restrict__ coef,
    const float* __restrict__ sb, const float* __restrict__ ss,
    const float* __restrict__ mk, float* __restrict__ out)
{
    __shared__ f32x4 v_s[IN];
    __shared__ float base_s[IN];
    __shared__ int   comb_s[IN];
    __shared__ float xn_s[IN];
    __shared__ float ps_t[OUTD * ICP];
    __shared__ float pa_t[OUTD * ICP];

    const int b = blockIdx.x;
    const int t = threadIdx.x;
    {
        float xv  = x[(size_t)b * IN + t];
        float xn  = tanhf(2.0f * xv);
        float sig = 1.0f / (1.0f + expf(-xn));
        float base = xn * sig;
        float pos  = (xn + 1.0f) * 4.0f;
        float fidx = fminf(fmaxf(floorf(pos), 0.0f), 7.0f);
        float u    = pos - fidx;
        int   idx  = (int)fidx;
        float u2 = u * u, u3 = u2 * u;
        const float c6 = 1.0f / 6.0f;
        f32x4 v;
        v.x = (1.0f - 3.0f * u + 3.0f * u2 - u3) * c6;
        v.y = (4.0f - 6.0f * u2 + 3.0f * u3) * c6;
        v.z = (1.0f + 3.0f * u + 3.0f * u2 - 3.0f * u3) * c6;
        v.w = u3 * c6;
        v_s[t] = v; base_s[t] = base;
        comb_s[t] = t * (OUTD * NC) + idx;
        xn_s[t] = xn;
    }
    __syncthreads();

    float* y    = out;
    float* pre  = out + (size_t)BATCH * OUTD;
    float* pact = pre  + (size_t)BATCH * OUTD * IN;
    float* pspl = pact + (size_t)BATCH * OUTD * IN;
    {
        f32x4 myxn = ((const f32x4*)xn_s)[t & 63];
        f32x4* dst = (f32x4*)(pre + (size_t)b * OUTD * IN);
        #pragma unroll 8
        for (int c = 0; c < 64; ++c)
            __builtin_nontemporal_store(myxn, dst + c * 256 + t);
    }
    float yacc = 0.0f;
    const int o = t;
    const int oNC = o * NC;
    const size_t bbase = (size_t)b * OUTD * IN;
    for (int ic = 0; ic < IN / IC; ++ic) {
        #pragma unroll
        for (int ii = 0; ii < IC; ++ii) {
            const int i = ic * IC + ii;
            f32x4 v = v_s[i];
            const float* cp = coef + comb_s[i] + oNC;
            float spl = cp[0] * v.x + cp[1] * v.y + cp[2] * v.z + cp[3] * v.w;
            const int io = i * OUTD + o;
            float yf = mk[io] * (sb[io] * base_s[i] + ss[io] * spl);
            yacc += yf;
            ps_t[o * ICP + ii] = spl;
            pa_t[o * ICP + ii] = yf;
        }
        __syncthreads();
        #pragma unroll
        for (int c = 0; c < 4; ++c) {
            const int f  = c * 256 + t;
            const int oo = f >> 2;
            const int i4 = (f & 3) * 4;
            const int la = oo * ICP + i4;
            f32x4 vps, vpa;
            vps.x = ps_t[la]; vps.y = ps_t[la+1]; vps.z = ps_t[la+2]; vps.w = ps_t[la+3];
            vpa.x = pa_t[la]; vpa.y = pa_t[la+1]; vpa.z = pa_t[la+2]; vpa.w = pa_t[la+3];
            const size_t g = bbase + (size_t)oo * IN + ic * IC + i4;
            __builtin_nontemporal_store(vps, (f32x4*)(pspl + g));
            __builtin_nontemporal_store(vpa, (f32x4*)(pact + g));
        }
        __syncthreads();
    }
    y[(size_t)b * OUTD + o] = yacc;
}

extern "C" void kernel_launch(void* const* d_in, const int* in_sizes, int n_in,
                              void* d_out, int out_size, void* d_ws, size_t ws_size,
                              hipStream_t stream) {
    const float* x    = (const float*)d_in[0];
    const float* coef = (const float*)d_in[1];
    const float* sb   = (const float*)d_in[2];
    const float* ss   = (const float*)d_in[3];
    const float* mk   = (const float*)d_in[4];
    float* out = (float*)d_out;

    const size_t coefT_bytes = (size_t)IN * NC * OUTD * sizeof(float);
    if (ws_size >= coefT_bytes) {
        float* coefT = (float*)d_ws;
        transpose_coef<<<IN, 256, 0, stream>>>(coef, coefT);
        kan_main<<<BATCH, 256, 0, stream>>>(x, coefT, sb, ss, mk, out);
    } else {
        kan_main_direct<<<BATCH, 256, 0, stream>>>(x, coef, sb, ss, mk, out);
    }
}